// Round 13
// baseline (521.550 us; speedup 1.0000x reference)
//
#include <hip/hip_runtime.h>
#include <hip/hip_bf16.h>
#include <cstdint>
#include <cstddef>

static constexpr int FD = 128;   // feature dim
static constexpr int NG = 16;    // graphs per batch
static constexpr int NL = 3;     // layers

typedef __attribute__((ext_vector_type(8))) short short8;
typedef __attribute__((ext_vector_type(4))) float floatx4;

__device__ __forceinline__ short f2bf(float v) {
  union { __hip_bfloat16 b; short s; } u;
  u.b = __float2bfloat16(v);
  return u.s;
}
__device__ __forceinline__ float bfu(unsigned short u) {
  return __uint_as_float((unsigned int)u << 16);
}

// ---------------- pass A: bucket edges by dst>>8, LDS-sorted staging ----------------
// entry = src | (dst<<16)  (requires N <= 65536)
__global__ __launch_bounds__(256) void k_bucket(
    const int* __restrict__ e0, const int* __restrict__ e1,
    int* __restrict__ gcount, int* __restrict__ buckets,
    int E, int NBUCK, int CAP)
{
  __shared__ int hist[256], lexcl[256], gbase[256], wcur[256];
  __shared__ int staged[4096];
  __shared__ int wsum[4];
  __shared__ int totalS;
  int tid = (int)threadIdx.x;
  int bx = (int)blockIdx.x;
  int t = bx & 1;
  int chunk = (bx >> 1) * 4096;
  const int* eg = t ? e1 : e0;
  hist[tid] = 0;
  __syncthreads();
  unsigned int ent[16];
  #pragma unroll
  for (int k = 0; k < 16; k++) {
    int i = chunk + k * 256 + tid;
    if (i < E) {
      unsigned int src = (unsigned int)eg[i];
      unsigned int dst = (unsigned int)eg[E + i];
      ent[k] = src | (dst << 16);
      atomicAdd(&hist[dst >> 8], 1);
    } else ent[k] = 0xFFFFFFFFu;
  }
  __syncthreads();
  // block scan of hist[256]
  int lane = tid & 63, wv = tid >> 6;
  int v = hist[tid];
  int sc = v;
  #pragma unroll
  for (int d = 1; d < 64; d <<= 1) {
    int tt = __shfl_up(sc, d, 64);
    if (lane >= d) sc += tt;
  }
  if (lane == 63) wsum[wv] = sc;
  __syncthreads();
  int wpre = 0;
  for (int w = 0; w < wv; w++) wpre += wsum[w];
  int excl = wpre + sc - v;
  lexcl[tid] = excl;
  wcur[tid] = excl;
  gbase[tid] = v ? atomicAdd(&gcount[t * 256 + tid], v) : 0;
  if (tid == 255) totalS = excl + v;
  __syncthreads();
  #pragma unroll
  for (int k = 0; k < 16; k++) {
    if (ent[k] != 0xFFFFFFFFu) {
      int b = ent[k] >> 24;
      int pos = atomicAdd(&wcur[b], 1);
      staged[pos] = (int)ent[k];
    }
  }
  __syncthreads();
  int total = totalS;
  for (int j = tid; j < total; j += 256) {
    unsigned int e = (unsigned int)staged[j];
    int b = e >> 24;
    int gp = gbase[b] + (j - lexcl[b]);
    if (gp < CAP) buckets[((size_t)t * NBUCK + b) * CAP + gp] = (int)e;
  }
}

// ---------------- pass B: per-bucket deg/off/csr with LDS atomics only ----------------
__global__ __launch_bounds__(256) void k_csr(
    const int* __restrict__ gcount, const int* __restrict__ buckets,
    unsigned short* __restrict__ csr0, unsigned short* __restrict__ csr1,
    int* __restrict__ off0, int* __restrict__ off1,
    int* __restrict__ deg0, int* __restrict__ deg1,
    int NBUCK, int CAP, int n)
{
  __shared__ int hist[256], wcur[256], wsum[4];
  int tid = (int)threadIdx.x;
  int bx = (int)blockIdx.x;
  int t = bx & 1;
  int b = bx >> 1;
  int cnt = gcount[t * 256 + b];
  if (cnt > CAP) cnt = CAP;
  const int* base = buckets + ((size_t)t * NBUCK + b) * CAP;
  unsigned short* csr = t ? csr1 : csr0;
  int* off = t ? off1 : off0;
  int* deg = t ? deg1 : deg0;
  hist[tid] = 0;
  __syncthreads();
  for (int j = tid; j < cnt; j += 256)
    atomicAdd(&hist[((unsigned int)base[j] >> 16) & 255], 1);
  __syncthreads();
  int lane = tid & 63, wv = tid >> 6;
  int v = hist[tid];
  int sc = v;
  #pragma unroll
  for (int d = 1; d < 64; d <<= 1) {
    int tt = __shfl_up(sc, d, 64);
    if (lane >= d) sc += tt;
  }
  if (lane == 63) wsum[wv] = sc;
  __syncthreads();
  int wpre = 0;
  for (int w = 0; w < wv; w++) wpre += wsum[w];
  int excl = wpre + sc - v;
  wcur[tid] = excl;
  int node = b * 256 + tid;
  if (node < n) { deg[node] = v; off[node] = b * CAP + excl; }
  __syncthreads();
  for (int j = tid; j < cnt; j += 256) {
    unsigned int e = (unsigned int)base[j];
    int ld = (e >> 16) & 255;
    int pos = atomicAdd(&wcur[ld], 1);
    csr[b * CAP + pos] = (unsigned short)(e & 0xFFFFu);
  }
}

// ---------------- merged conversion: W -> frag hi/lo, x -> row-major bf16 ----------------
// blocks [0,192): wconv; blocks [192, 192+2*NGRP): xconv
__global__ __launch_bounds__(256) void k_conv(
    const float* __restrict__ Wl, const float* __restrict__ Wr,
    short* __restrict__ Wf,
    const float* __restrict__ x0, const float* __restrict__ x1,
    short* __restrict__ r0, short* __restrict__ r1, int n) {
  int bx = (int)blockIdx.x;
  int tid = (int)threadIdx.x;
  if (bx < 192) {
    int u = bx * 256 + tid;
    int combo = u >> 13;
    int r = u & 8191;
    int l  = r & 63;
    int nt = (r >> 6) & 7;
    int h  = (r >> 9) & 1;
    int ks = r >> 10;
    short8 s;
    #pragma unroll
    for (int j = 0; j < 8; j++) {
      int k = ks * 32 + (l >> 4) * 8 + j;
      int nn = nt * 16 + (l & 15);
      float w = (k < FD) ? Wl[((size_t)combo * FD + k) * FD + nn]
                         : Wr[((size_t)combo * FD + (k - FD)) * FD + nn];
      __hip_bfloat16 hb = __float2bfloat16(w);
      if (h == 0) {
        union { __hip_bfloat16 b; short t; } uu; uu.b = hb; s[j] = uu.t;
      } else {
        float hf = __bfloat162float(hb);
        s[j] = f2bf(w - hf);
      }
    }
    *(short8*)(Wf + (size_t)combo * 65536 + (size_t)r * 8) = s;
  } else {
    int b2 = bx - 192;
    int t = b2 & 1;
    int g = b2 >> 1;
    const float* x = t ? x1 : x0;
    short* rm = t ? r1 : r0;
    int m = tid & 15;
    int kb = tid >> 4;          // 0..15
    int node = g * 16 + m;
    if (node >= n) return;
    const float* src = x + (size_t)node * FD + kb * 8;
    short8 s;
    #pragma unroll
    for (int j = 0; j < 8; j++) s[j] = f2bf(src[j]);
    *(short8*)(rm + (size_t)node * FD + kb * 8) = s;
  }
}

// ---------------- pipelined stage: gemm(type A) + agg(type B) in one dispatch ----------------
// blocks [0, gemmBlocks): MFMA gemm, 256 working threads (waves 4-7 run 12
// matched barriers). blocks [gemmBlocks, ...): agg, all 512 threads (R7 body).
// The two type-chains are independent; every data dep lands in an earlier
// dispatch (see host stage table).
__global__ __launch_bounds__(512, 4) void k_stage(
    const unsigned short* __restrict__ gmrm, const unsigned short* __restrict__ gxin,
    const short* __restrict__ gW, const float* __restrict__ gbias,
    short* __restrict__ gout, int gemmBlocks,
    const unsigned short* __restrict__ ax,
    const unsigned short* __restrict__ acsr,
    const int* __restrict__ aoff, const int* __restrict__ adeg,
    short* __restrict__ amrm, int n)
{
  __shared__ __align__(16) char smem[49152];
  int tid = (int)threadIdx.x;
  int bx = (int)blockIdx.x;

  if (bx < gemmBlocks) {
    // ================= GEMM path =================
    if (tid < 256) {
      short* AsL = (short*)smem;            // [2][4096] A dbuf (16 KB)
      short* WfL = (short*)(smem + 16384);  // [2][8192] W dbuf (32 KB)
      float* S   = (float*)smem;            // [128][64] epilogue scratch

      int l = tid & 63;
      int wv = tid >> 6;
      int row0 = bx * 128;
      int rhalf = wv & 1;
      int chalf = wv >> 1;

      auto stageA = [&](int ks, int buf) {
        const unsigned short* Ab = (ks < 4) ? gmrm : gxin;
        int kc = (ks & 3) * 32;
        #pragma unroll
        for (int i = 0; i < 2; i++) {
          int g16 = wv * 2 + i;
          const unsigned short* g =
              Ab + (size_t)(row0 + g16 * 16 + (l & 15)) * FD + kc + (l >> 4) * 8;
          __builtin_amdgcn_global_load_lds(
              (const __attribute__((address_space(1))) void*)g,
              (__attribute__((address_space(3))) void*)(AsL + buf * 4096 + g16 * 512),
              16, 0, 0);
        }
      };
      auto stageW = [&](int ks, int buf) {
        const short* src = gW + ks * 8192 + wv * 2048;
        short* dst = WfL + buf * 8192 + wv * 2048;
        #pragma unroll
        for (int i = 0; i < 4; i++) {
          __builtin_amdgcn_global_load_lds(
              (const __attribute__((address_space(1))) void*)(src + i * 512 + l * 8),
              (__attribute__((address_space(3))) void*)(dst + i * 512),
              16, 0, 0);
        }
      };

      floatx4 acc[4][4];
      #pragma unroll
      for (int i = 0; i < 4; i++)
        #pragma unroll
        for (int q = 0; q < 4; q++) acc[i][q] = (floatx4)0.f;

      stageA(0, 0);
      stageW(0, 0);
      for (int ks = 0; ks < 8; ks++) {
        int buf = ks & 1;
        __syncthreads();                 // [sync 1..8]
        if (ks < 7) { stageA(ks + 1, buf ^ 1); stageW(ks + 1, buf ^ 1); }
        short8 Areg[4];
        #pragma unroll
        for (int i = 0; i < 4; i++)
          Areg[i] = *(const short8*)(AsL + buf * 4096 + (rhalf * 4 + i) * 512 + l * 8);
        const short* WB = WfL + buf * 8192;
        #pragma unroll
        for (int q = 0; q < 4; q++) {
          int nt = chalf * 4 + q;
          short8 whi = *(const short8*)(WB + nt * 512 + l * 8);
          short8 wlo = *(const short8*)(WB + 4096 + nt * 512 + l * 8);
          #pragma unroll
          for (int i = 0; i < 4; i++) {
            acc[i][q] = __builtin_amdgcn_mfma_f32_16x16x32_bf16(Areg[i], whi, acc[i][q], 0, 0, 0);
            acc[i][q] = __builtin_amdgcn_mfma_f32_16x16x32_bf16(Areg[i], wlo, acc[i][q], 0, 0, 0);
          }
        }
      }

      #pragma unroll
      for (int q = 0; q < 4; q++) {
        int col = chalf * 64 + q * 16 + (l & 15);
        float b = gbias[col];
        #pragma unroll
        for (int i = 0; i < 4; i++)
          #pragma unroll
          for (int r = 0; r < 4; r++)
            acc[i][q][r] = fmaxf(acc[i][q][r] + b, 0.f);
      }

      #pragma unroll
      for (int ph = 0; ph < 2; ph++) {
        __syncthreads();                 // [sync 9,11]
        if (chalf == ph) {
          #pragma unroll
          for (int i = 0; i < 4; i++)
            #pragma unroll
            for (int q = 0; q < 4; q++)
              #pragma unroll
              for (int r = 0; r < 4; r++)
                S[(rhalf * 64 + i * 16 + (l >> 4) * 4 + r) * 64 + q * 16 + (l & 15)] = acc[i][q][r];
        }
        __syncthreads();                 // [sync 10,12]
        #pragma unroll
        for (int it = 0; it < 4; it++) {
          int u = it * 256 + tid;
          int m = u & 15;
          int kb = (u >> 4) & 7;
          int grp = u >> 7;
          int rl = grp * 16 + m;
          if (row0 + rl < n) {
            short8 s;
            #pragma unroll
            for (int j = 0; j < 8; j++) s[j] = f2bf(S[rl * 64 + kb * 8 + j]);
            *(short8*)(gout + (size_t)(row0 + rl) * FD + ph * 64 + kb * 8) = s;
          }
        }
      }
    } else {
      #pragma unroll
      for (int i = 0; i < 12; i++) __syncthreads();   // matched barrier count
    }
  } else {
    // ================= AGG path (R7-proven body, single type) =================
    float (*M)[132] = (float(*)[132])smem;
    int g = bx - gemmBlocks;
    int s = tid >> 5;             // node slot 0..15
    int tx = tid & 31;
    int c4 = tx * 4;
    int node = g * 16 + s;
    if (node < n) {
      int o = aoff[node], d = adeg[node];
      float a0 = 0.f, a1 = 0.f, a2 = 0.f, a3 = 0.f;
      for (int k0 = 0; k0 < d; k0 += 32) {
        int idx = (k0 + tx < d) ? (int)acsr[o + k0 + tx] : 0;
        int mm = min(32, d - k0);
        int j = 0;
        for (; j + 8 <= mm; j += 8) {
          int s0 = __shfl(idx, j + 0, 32);
          int s1 = __shfl(idx, j + 1, 32);
          int s2 = __shfl(idx, j + 2, 32);
          int s3 = __shfl(idx, j + 3, 32);
          int s4 = __shfl(idx, j + 4, 32);
          int s5 = __shfl(idx, j + 5, 32);
          int s6 = __shfl(idx, j + 6, 32);
          int s7 = __shfl(idx, j + 7, 32);
          ushort4 u0 = *(const ushort4*)&ax[(size_t)s0 * FD + c4];
          ushort4 u1 = *(const ushort4*)&ax[(size_t)s1 * FD + c4];
          ushort4 u2 = *(const ushort4*)&ax[(size_t)s2 * FD + c4];
          ushort4 u3 = *(const ushort4*)&ax[(size_t)s3 * FD + c4];
          ushort4 u4 = *(const ushort4*)&ax[(size_t)s4 * FD + c4];
          ushort4 u5 = *(const ushort4*)&ax[(size_t)s5 * FD + c4];
          ushort4 u6 = *(const ushort4*)&ax[(size_t)s6 * FD + c4];
          ushort4 u7 = *(const ushort4*)&ax[(size_t)s7 * FD + c4];
          a0 += ((bfu(u0.x) + bfu(u1.x)) + (bfu(u2.x) + bfu(u3.x)))
              + ((bfu(u4.x) + bfu(u5.x)) + (bfu(u6.x) + bfu(u7.x)));
          a1 += ((bfu(u0.y) + bfu(u1.y)) + (bfu(u2.y) + bfu(u3.y)))
              + ((bfu(u4.y) + bfu(u5.y)) + (bfu(u6.y) + bfu(u7.y)));
          a2 += ((bfu(u0.z) + bfu(u1.z)) + (bfu(u2.z) + bfu(u3.z)))
              + ((bfu(u4.z) + bfu(u5.z)) + (bfu(u6.z) + bfu(u7.z)));
          a3 += ((bfu(u0.w) + bfu(u1.w)) + (bfu(u2.w) + bfu(u3.w)))
              + ((bfu(u4.w) + bfu(u5.w)) + (bfu(u6.w) + bfu(u7.w)));
        }
        for (; j < mm; j++) {
          int si = __shfl(idx, j, 32);
          ushort4 u = *(const ushort4*)&ax[(size_t)si * FD + c4];
          a0 += bfu(u.x); a1 += bfu(u.y); a2 += bfu(u.z); a3 += bfu(u.w);
        }
      }
      float inv = 1.f / fmaxf((float)d, 1.f);
      M[s][c4 + 0] = a0 * inv;
      M[s][c4 + 1] = a1 * inv;
      M[s][c4 + 2] = a2 * inv;
      M[s][c4 + 3] = a3 * inv;
    }
    __syncthreads();
    if (tid < 256) {
      int m = tid & 15;
      int kb = tid >> 4;
      int nd = g * 16 + m;
      if (nd < n) {
        short8 v;
        #pragma unroll
        for (int j = 0; j < 8; j++) v[j] = f2bf(M[m][kb * 8 + j]);
        *(short8*)(amrm + (size_t)nd * FD + kb * 8) = v;
      }
    }
  }
}

// ---------------- pool stage 1: dense per-chunk partials, no atomics ----------------
__global__ __launch_bounds__(256) void k_pool1(
    const unsigned short* __restrict__ x0, const unsigned short* __restrict__ x1,
    const int* __restrict__ b0, const int* __restrict__ b1,
    float* __restrict__ part, int n, int NCH) {
  __shared__ float R[8][128];
  __shared__ int sb;
  int bx = (int)blockIdx.x;
  int t = bx & 1;
  int ch = bx >> 1;
  const unsigned short* x = t ? x1 : x0;
  const int* batch = t ? b1 : b0;
  float* P = part + ((size_t)t * NCH + ch) * 272;
  int tid = (int)threadIdx.x;
  int tx = tid & 31, rs = tid >> 5;
  int c4 = tx * 4;
  int start = ch * 128;
  int end = min(start + 128, n);

  int g0 = batch[start];
  int g1 = batch[end - 1];
  int lo[2], hi[2];
  int nruns;
  if (g0 == g1) {
    lo[0] = start; hi[0] = end; nruns = 1;
  } else {
    if (tid == 0) sb = end;
    __syncthreads();
    for (int i = start + tid + 1; i < end; i += 256)
      if (batch[i] != batch[i - 1]) atomicMin(&sb, i);
    __syncthreads();
    int b = sb;
    lo[0] = start; hi[0] = b; lo[1] = b; hi[1] = end; nruns = 2;
  }

  for (int run = 0; run < nruns; run++) {
    float4 a = make_float4(0.f, 0.f, 0.f, 0.f);
    for (int i = lo[run] + rs; i < hi[run]; i += 8) {
      ushort4 u = *(const ushort4*)&x[(size_t)i * FD + c4];
      a.x += bfu(u.x); a.y += bfu(u.y); a.z += bfu(u.z); a.w += bfu(u.w);
    }
    *(float4*)&R[rs][c4] = a;
    __syncthreads();
    if (tid < 128) {
      float s = 0.f;
      #pragma unroll
      for (int r = 0; r < 8; r++) s += R[r][tid];
      P[run * 128 + tid] = s;
    }
    __syncthreads();
  }
  if (tid == 0) {
    P[256] = (float)g0;
    P[257] = (float)(hi[0] - lo[0]);
    P[258] = (nruns == 2) ? (float)g1 : -1.f;
    P[259] = (nruns == 2) ? (float)(hi[1] - lo[1]) : 0.f;
  }
}

// ---------------- pool stage 2: reduce chunk partials (few atomics) ----------------
__global__ __launch_bounds__(128) void k_pool2(
    const float* __restrict__ part, float* __restrict__ pool,
    float* __restrict__ pcnt, int NCH, int CPS) {
  int bx = (int)blockIdx.x;
  int t = bx & 1;
  int seg = bx >> 1;
  int c0 = seg * CPS;
  int c1 = min(c0 + CPS, NCH);
  int tid = (int)threadIdx.x;
  float* pl = pool + t * NG * FD;
  float* pc = pcnt + t * NG;
  float acc = 0.f, ccnt = 0.f;
  int curg = -1;
  for (int ch = c0; ch < c1; ch++) {
    const float* P = part + ((size_t)t * NCH + ch) * 272;
    #pragma unroll
    for (int r = 0; r < 2; r++) {
      int g = (int)P[256 + r * 2];
      if (g < 0) continue;
      if (g != curg) {
        if (curg >= 0) {
          atomicAdd(&pl[curg * FD + tid], acc);
          if (tid == 0) atomicAdd(&pc[curg], ccnt);
        }
        curg = g; acc = 0.f; ccnt = 0.f;
      }
      acc += P[r * 128 + tid];
      if (tid == 0) ccnt += P[257 + r * 2];
    }
  }
  if (curg >= 0) {
    atomicAdd(&pl[curg * FD + tid], acc);
    if (tid == 0) atomicAdd(&pc[curg], ccnt);
  }
}

// ---------------- head ----------------
__global__ void k_final(const float* __restrict__ pool, const float* __restrict__ pcnt,
                        const float* __restrict__ linW, const float* __restrict__ linb,
                        float* __restrict__ out) {
  int tid = (int)threadIdx.x;
  if (tid < NG * 2) {
    int g = tid >> 1, o = tid & 1;
    float s = linb[o];
    for (int t = 0; t < 2; t++) {
      float inv = 1.f / fmaxf(pcnt[t * NG + g], 1.f);
      for (int d = 0; d < FD; d++) {
        float h = pool[(t * NG + g) * FD + d] * inv;
        s = fmaf(h, linW[(t * FD + d) * 2 + o], s);
      }
    }
    out[g * 2 + o] = s;
  }
}

extern "C" void kernel_launch(void* const* d_in, const int* in_sizes, int n_in,
                              void* d_out, int out_size, void* d_ws, size_t ws_size,
                              hipStream_t stream) {
  const float* x_in[2] = {(const float*)d_in[0], (const float*)d_in[1]};
  const float* Wl   = (const float*)d_in[2];
  const float* bl   = (const float*)d_in[3];
  const float* Wr   = (const float*)d_in[4];
  const float* linW = (const float*)d_in[5];
  const float* linb = (const float*)d_in[6];
  const int* edges[2] = {(const int*)d_in[7], (const int*)d_in[8]};
  const int* batch[2] = {(const int*)d_in[9], (const int*)d_in[10]};

  const int N = in_sizes[0] / FD;    // 50000
  const int E = in_sizes[7] / 2;     // 800000
  const int NGRP = (N + 15) / 16;    // 3125
  const int NTILE = (N + 127) / 128; // 391
  const int NCH = (N + 127) / 128;   // 391
  const int NBUCK = (N + 255) / 256; // 196
  const int CAP = 5120;              // per-bucket capacity (avg ~4096)
  const int NPAD = NTILE * 128;      // padded node count (A reads stay in-bounds)

  // ---- workspace layout (512B aligned) ----
  char* p = (char*)d_ws;
  auto alloc = [&](size_t bytes) -> char* {
    char* r = p; p += (bytes + 511) & ~(size_t)511; return r;
  };
  int* gcount  = (int*)alloc(2 * 256 * 4);
  float* pool  = (float*)alloc(2 * NG * FD * 4);
  float* pcnt  = (float*)alloc(2 * NG * 4);
  size_t zero_bytes = (size_t)(p - (char*)d_ws);       // gcount+pool+pcnt
  int* off[2];  off[0]  = (int*)alloc((size_t)N * 4); off[1]  = (int*)alloc((size_t)N * 4);
  int* deg[2];  deg[0]  = (int*)alloc((size_t)N * 4); deg[1]  = (int*)alloc((size_t)N * 4);
  int* buckets = (int*)alloc((size_t)2 * NBUCK * CAP * 4);
  unsigned short* csr[2];
  csr[0] = (unsigned short*)alloc((size_t)NBUCK * CAP * 2);
  csr[1] = (unsigned short*)alloc((size_t)NBUCK * CAP * 2);
  float* part  = (float*)alloc((size_t)2 * NCH * 272 * 4);
  short* Wf    = (short*)alloc((size_t)6 * 65536 * 2);
  short* meanb[2];
  meanb[0] = (short*)alloc((size_t)NPAD * FD * 2);
  meanb[1] = (short*)alloc((size_t)NPAD * FD * 2);
  short* xbf[2][2];
  for (int t = 0; t < 2; t++)
    for (int b = 0; b < 2; b++) xbf[t][b] = (short*)alloc((size_t)NPAD * FD * 2);
  if ((size_t)(p - (char*)d_ws) > ws_size) return;     // insufficient workspace

  hipMemsetAsync(d_ws, 0, zero_bytes, stream);

  // conversions (merged) + CSR build
  k_conv<<<192 + 2 * NGRP, 256, 0, stream>>>(Wl, Wr, Wf, x_in[0], x_in[1],
                                             xbf[0][0], xbf[1][0], N);
  int bblocks = 2 * ((E + 4095) / 4096);
  k_bucket<<<bblocks, 256, 0, stream>>>(edges[0], edges[1], gcount, buckets, E, NBUCK, CAP);
  k_csr<<<2 * NBUCK, 256, 0, stream>>>(gcount, buckets, csr[0], csr[1],
                                       off[0], off[1], deg[0], deg[1], NBUCK, CAP, N);

  // ---- pipelined layer stages: {agg type, gemm type, gemm layer} ----
  // deps always land in a strictly earlier dispatch (independent type-chains).
  struct Stg { int ta, tg, gl; };
  const Stg stages[7] = {
    {0, -1, -1},  // S0: agg(t0,l0)
    {1,  0,  0},  // S1: agg(t1,l0) + gemm(t0,l0)
    {0,  1,  0},  // S2: agg(t0,l1) + gemm(t1,l0)
    {1,  0,  1},  // S3: agg(t1,l1) + gemm(t0,l1)
    {0,  1,  1},  // S4: agg(t0,l2) + gemm(t1,l1)
    {1,  0,  2},  // S5: agg(t1,l2) + gemm(t0,l2)
    {-1, 1,  2},  // S6: gemm(t1,l2)
  };
  int pp[2] = {0, 0};
  for (int s = 0; s < 7; s++) {
    int ta = stages[s].ta, tg = stages[s].tg, gl = stages[s].gl;
    const unsigned short *ax = nullptr, *acsr = nullptr;
    const int *aoff = nullptr, *adeg = nullptr;
    short* amrm = nullptr;
    int ab = 0;
    if (ta >= 0) {
      ax = (const unsigned short*)xbf[ta][pp[ta]];
      acsr = csr[ta]; aoff = off[ta]; adeg = deg[ta];
      amrm = meanb[ta];
      ab = NGRP;
    }
    const unsigned short *gm = nullptr, *gx = nullptr;
    const short* gW = nullptr;
    const float* gb = nullptr;
    short* go = nullptr;
    int gbk = 0;
    if (tg >= 0) {
      gm = (const unsigned short*)meanb[tg];
      gx = (const unsigned short*)xbf[tg][pp[tg]];
      gW = Wf + (size_t)(gl * 2 + tg) * 65536;
      gb = bl + (size_t)(gl * 2 + tg) * FD;
      go = xbf[tg][pp[tg] ^ 1];
      gbk = NTILE;
    }
    k_stage<<<gbk + ab, 512, 0, stream>>>(gm, gx, gW, gb, go, gbk,
                                          ax, acsr, aoff, adeg, amrm, N);
    if (tg >= 0) pp[tg] ^= 1;
  }

  k_pool1<<<2 * NCH, 256, 0, stream>>>(
      (const unsigned short*)xbf[0][pp[0]], (const unsigned short*)xbf[1][pp[1]],
      batch[0], batch[1], part, N, NCH);
  int CPS = (NCH + 7) / 8;
  k_pool2<<<16, 128, 0, stream>>>(part, pool, pcnt, NCH, CPS);
  k_final<<<1, 64, 0, stream>>>(pool, pcnt, linW, linb, (float*)d_out);
}

// Round 14
// 416.383 us; speedup vs baseline: 1.2526x; 1.2526x over previous
//
#include <hip/hip_runtime.h>
#include <hip/hip_bf16.h>
#include <hip/hip_fp8.h>
#include <cstdint>
#include <cstddef>

static constexpr int FD = 128;   // feature dim
static constexpr int NG = 16;    // graphs per batch
static constexpr int NL = 3;     // layers

typedef __attribute__((ext_vector_type(8))) short short8;
typedef __attribute__((ext_vector_type(4))) float floatx4;

__device__ __forceinline__ short f2bf(float v) {
  union { __hip_bfloat16 b; short s; } u;
  u.b = __float2bfloat16(v);
  return u.s;
}
__device__ __forceinline__ float bfu(unsigned short u) {
  return __uint_as_float((unsigned int)u << 16);
}
__device__ __forceinline__ unsigned char ftof8(float v) {
  __hip_fp8_e4m3 f(v);
  return f.__x;
}
__device__ __forceinline__ float f8tof(unsigned char v) {
  __hip_fp8_e4m3 f;
  f.__x = v;
  return (float)f;
}

// ---------------- pass A: bucket edges by dst>>8, LDS-sorted staging ----------------
// entry = src | (dst<<16)  (requires N <= 65536)
__global__ __launch_bounds__(256) void k_bucket(
    const int* __restrict__ e0, const int* __restrict__ e1,
    int* __restrict__ gcount, int* __restrict__ buckets,
    int E, int NBUCK, int CAP)
{
  __shared__ int hist[256], lexcl[256], gbase[256], wcur[256];
  __shared__ int staged[4096];
  __shared__ int wsum[4];
  __shared__ int totalS;
  int tid = (int)threadIdx.x;
  int bx = (int)blockIdx.x;
  int t = bx & 1;
  int chunk = (bx >> 1) * 4096;
  const int* eg = t ? e1 : e0;
  hist[tid] = 0;
  __syncthreads();
  unsigned int ent[16];
  #pragma unroll
  for (int k = 0; k < 16; k++) {
    int i = chunk + k * 256 + tid;
    if (i < E) {
      unsigned int src = (unsigned int)eg[i];
      unsigned int dst = (unsigned int)eg[E + i];
      ent[k] = src | (dst << 16);
      atomicAdd(&hist[dst >> 8], 1);
    } else ent[k] = 0xFFFFFFFFu;
  }
  __syncthreads();
  // block scan of hist[256]
  int lane = tid & 63, wv = tid >> 6;
  int v = hist[tid];
  int sc = v;
  #pragma unroll
  for (int d = 1; d < 64; d <<= 1) {
    int tt = __shfl_up(sc, d, 64);
    if (lane >= d) sc += tt;
  }
  if (lane == 63) wsum[wv] = sc;
  __syncthreads();
  int wpre = 0;
  for (int w = 0; w < wv; w++) wpre += wsum[w];
  int excl = wpre + sc - v;
  lexcl[tid] = excl;
  wcur[tid] = excl;
  gbase[tid] = v ? atomicAdd(&gcount[t * 256 + tid], v) : 0;
  if (tid == 255) totalS = excl + v;
  __syncthreads();
  #pragma unroll
  for (int k = 0; k < 16; k++) {
    if (ent[k] != 0xFFFFFFFFu) {
      int b = ent[k] >> 24;
      int pos = atomicAdd(&wcur[b], 1);
      staged[pos] = (int)ent[k];
    }
  }
  __syncthreads();
  int total = totalS;
  for (int j = tid; j < total; j += 256) {
    unsigned int e = (unsigned int)staged[j];
    int b = e >> 24;
    int gp = gbase[b] + (j - lexcl[b]);
    if (gp < CAP) buckets[((size_t)t * NBUCK + b) * CAP + gp] = (int)e;
  }
}

// ---------------- pass B: per-bucket deg/off/csr with LDS atomics only ----------------
__global__ __launch_bounds__(256) void k_csr(
    const int* __restrict__ gcount, const int* __restrict__ buckets,
    unsigned short* __restrict__ csr0, unsigned short* __restrict__ csr1,
    int* __restrict__ off0, int* __restrict__ off1,
    int* __restrict__ deg0, int* __restrict__ deg1,
    int NBUCK, int CAP, int n)
{
  __shared__ int hist[256], wcur[256], wsum[4];
  int tid = (int)threadIdx.x;
  int bx = (int)blockIdx.x;
  int t = bx & 1;
  int b = bx >> 1;
  int cnt = gcount[t * 256 + b];
  if (cnt > CAP) cnt = CAP;
  const int* base = buckets + ((size_t)t * NBUCK + b) * CAP;
  unsigned short* csr = t ? csr1 : csr0;
  int* off = t ? off1 : off0;
  int* deg = t ? deg1 : deg0;
  hist[tid] = 0;
  __syncthreads();
  for (int j = tid; j < cnt; j += 256)
    atomicAdd(&hist[((unsigned int)base[j] >> 16) & 255], 1);
  __syncthreads();
  int lane = tid & 63, wv = tid >> 6;
  int v = hist[tid];
  int sc = v;
  #pragma unroll
  for (int d = 1; d < 64; d <<= 1) {
    int tt = __shfl_up(sc, d, 64);
    if (lane >= d) sc += tt;
  }
  if (lane == 63) wsum[wv] = sc;
  __syncthreads();
  int wpre = 0;
  for (int w = 0; w < wv; w++) wpre += wsum[w];
  int excl = wpre + sc - v;
  wcur[tid] = excl;
  int node = b * 256 + tid;
  if (node < n) { deg[node] = v; off[node] = b * CAP + excl; }
  __syncthreads();
  for (int j = tid; j < cnt; j += 256) {
    unsigned int e = (unsigned int)base[j];
    int ld = (e >> 16) & 255;
    int pos = atomicAdd(&wcur[ld], 1);
    csr[b * CAP + pos] = (unsigned short)(e & 0xFFFFu);
  }
}

// ---------------- merged conversion: W -> frag hi/lo, x -> bf16 + fp8 ----------------
// blocks [0,192): wconv; blocks [192, 192+2*NGRP): xconv
__global__ __launch_bounds__(256) void k_conv(
    const float* __restrict__ Wl, const float* __restrict__ Wr,
    short* __restrict__ Wf,
    const float* __restrict__ x0, const float* __restrict__ x1,
    short* __restrict__ r0, short* __restrict__ r1,
    unsigned char* __restrict__ q0, unsigned char* __restrict__ q1, int n) {
  int bx = (int)blockIdx.x;
  int tid = (int)threadIdx.x;
  if (bx < 192) {
    int u = bx * 256 + tid;
    int combo = u >> 13;
    int r = u & 8191;
    int l  = r & 63;
    int nt = (r >> 6) & 7;
    int h  = (r >> 9) & 1;
    int ks = r >> 10;
    short8 s;
    #pragma unroll
    for (int j = 0; j < 8; j++) {
      int k = ks * 32 + (l >> 4) * 8 + j;
      int nn = nt * 16 + (l & 15);
      float w = (k < FD) ? Wl[((size_t)combo * FD + k) * FD + nn]
                         : Wr[((size_t)combo * FD + (k - FD)) * FD + nn];
      __hip_bfloat16 hb = __float2bfloat16(w);
      if (h == 0) {
        union { __hip_bfloat16 b; short t; } uu; uu.b = hb; s[j] = uu.t;
      } else {
        float hf = __bfloat162float(hb);
        s[j] = f2bf(w - hf);
      }
    }
    *(short8*)(Wf + (size_t)combo * 65536 + (size_t)r * 8) = s;
  } else {
    int b2 = bx - 192;
    int t = b2 & 1;
    int g = b2 >> 1;
    const float* x = t ? x1 : x0;
    short* rm = t ? r1 : r0;
    unsigned char* qm = t ? q1 : q0;
    int m = tid & 15;
    int kb = tid >> 4;          // 0..15
    int node = g * 16 + m;
    if (node >= n) return;
    const float* src = x + (size_t)node * FD + kb * 8;
    short8 s;
    union { unsigned char c[8]; uint2 u; } e8;
    #pragma unroll
    for (int j = 0; j < 8; j++) {
      float v = src[j];
      s[j] = f2bf(v);
      e8.c[j] = ftof8(v);
    }
    *(short8*)(rm + (size_t)node * FD + kb * 8) = s;
    *(uint2*)(qm + (size_t)node * FD + kb * 8) = e8.u;
  }
}

// ---------------- neighbor mean from fp8 rows -> row-major bf16 mean ----------------
// 16 nodes/block, 512 threads, 32 lanes/node, 8-deep gather pipeline.
// fp8 rows = 128B = 2 cache lines/edge (half the in-flight lines of bf16).
__global__ __launch_bounds__(512) void k_agg(
    const unsigned char* __restrict__ x0, const unsigned char* __restrict__ x1,
    const unsigned short* __restrict__ csr0, const unsigned short* __restrict__ csr1,
    const int* __restrict__ off0, const int* __restrict__ off1,
    const int* __restrict__ deg0, const int* __restrict__ deg1,
    short* __restrict__ m0, short* __restrict__ m1, int n)
{
  __shared__ float M[16][132];
  int bx = blockIdx.x;
  int t = bx & 1;
  int g = bx >> 1;
  const unsigned char* x = t ? x1 : x0;
  const unsigned short* csr = t ? csr1 : csr0;
  const int* off  = t ? off1 : off0;
  const int* deg  = t ? deg1 : deg0;
  short* mrm      = t ? m1 : m0;
  int tid = (int)threadIdx.x;
  int s = tid >> 5;             // node slot 0..15
  int tx = tid & 31;
  int c4 = tx * 4;
  int node = g * 16 + s;
  if (node < n) {
    int o = off[node], d = deg[node];
    float a0 = 0.f, a1 = 0.f, a2 = 0.f, a3 = 0.f;
    for (int k0 = 0; k0 < d; k0 += 32) {
      int idx = (k0 + tx < d) ? (int)csr[o + k0 + tx] : 0;
      int mm = min(32, d - k0);
      int j = 0;
      for (; j + 8 <= mm; j += 8) {
        int s0 = __shfl(idx, j + 0, 32);
        int s1 = __shfl(idx, j + 1, 32);
        int s2 = __shfl(idx, j + 2, 32);
        int s3 = __shfl(idx, j + 3, 32);
        int s4 = __shfl(idx, j + 4, 32);
        int s5 = __shfl(idx, j + 5, 32);
        int s6 = __shfl(idx, j + 6, 32);
        int s7 = __shfl(idx, j + 7, 32);
        uchar4 u0 = *(const uchar4*)&x[(size_t)s0 * FD + c4];
        uchar4 u1 = *(const uchar4*)&x[(size_t)s1 * FD + c4];
        uchar4 u2 = *(const uchar4*)&x[(size_t)s2 * FD + c4];
        uchar4 u3 = *(const uchar4*)&x[(size_t)s3 * FD + c4];
        uchar4 u4 = *(const uchar4*)&x[(size_t)s4 * FD + c4];
        uchar4 u5 = *(const uchar4*)&x[(size_t)s5 * FD + c4];
        uchar4 u6 = *(const uchar4*)&x[(size_t)s6 * FD + c4];
        uchar4 u7 = *(const uchar4*)&x[(size_t)s7 * FD + c4];
        a0 += ((f8tof(u0.x) + f8tof(u1.x)) + (f8tof(u2.x) + f8tof(u3.x)))
            + ((f8tof(u4.x) + f8tof(u5.x)) + (f8tof(u6.x) + f8tof(u7.x)));
        a1 += ((f8tof(u0.y) + f8tof(u1.y)) + (f8tof(u2.y) + f8tof(u3.y)))
            + ((f8tof(u4.y) + f8tof(u5.y)) + (f8tof(u6.y) + f8tof(u7.y)));
        a2 += ((f8tof(u0.z) + f8tof(u1.z)) + (f8tof(u2.z) + f8tof(u3.z)))
            + ((f8tof(u4.z) + f8tof(u5.z)) + (f8tof(u6.z) + f8tof(u7.z)));
        a3 += ((f8tof(u0.w) + f8tof(u1.w)) + (f8tof(u2.w) + f8tof(u3.w)))
            + ((f8tof(u4.w) + f8tof(u5.w)) + (f8tof(u6.w) + f8tof(u7.w)));
      }
      for (; j < mm; j++) {
        int si = __shfl(idx, j, 32);
        uchar4 u = *(const uchar4*)&x[(size_t)si * FD + c4];
        a0 += f8tof(u.x); a1 += f8tof(u.y); a2 += f8tof(u.z); a3 += f8tof(u.w);
      }
    }
    float inv = 1.f / fmaxf((float)d, 1.f);
    M[s][c4 + 0] = a0 * inv;
    M[s][c4 + 1] = a1 * inv;
    M[s][c4 + 2] = a2 * inv;
    M[s][c4 + 3] = a3 * inv;
  }
  __syncthreads();
  if (tid < 256) {
    int m = tid & 15;
    int kb = tid >> 4;          // 0..15
    int nd = g * 16 + m;
    if (nd < n) {
      short8 v;
      #pragma unroll
      for (int j = 0; j < 8; j++) v[j] = f2bf(M[m][kb * 8 + j]);
      *(short8*)(mrm + (size_t)nd * FD + kb * 8) = v;
    }
  }
}

// ---------------- MFMA GEMM: y = relu([mean|x] @ [Wl;Wr] + b) -> bf16 + fp8 ----------------
__global__ __launch_bounds__(256) void k_gemm(
    const unsigned short* __restrict__ mrm0, const unsigned short* __restrict__ mrm1,
    const unsigned short* __restrict__ xin0, const unsigned short* __restrict__ xin1,
    const short* __restrict__ Wf,       // layer base: [2 types][65536]
    const float* __restrict__ bl,       // layer base: [2 types][128]
    short* __restrict__ obf0, short* __restrict__ obf1,
    unsigned char* __restrict__ oq0, unsigned char* __restrict__ oq1, int n)
{
  __shared__ __align__(16) char smem[49152];
  short* AsL = (short*)smem;            // [2][4096] A dbuf (16 KB)
  short* WfL = (short*)(smem + 16384);  // [2][8192] W dbuf (32 KB)
  float* S   = (float*)smem;            // [128][64] epilogue scratch (after loop)

  int tid = (int)threadIdx.x;
  int l = tid & 63;
  int wv = tid >> 6;
  int bx = (int)blockIdx.x;
  int t = bx & 1;
  int tile = bx >> 1;
  int row0 = tile * 128;

  const unsigned short* mrm = t ? mrm1 : mrm0;
  const unsigned short* xin = t ? xin1 : xin0;
  const short* Wc  = Wf + (size_t)t * 65536;
  const float* bias = bl + t * FD;
  short* obf = t ? obf1 : obf0;
  unsigned char* oq = t ? oq1 : oq0;

  int rhalf = wv & 1;
  int chalf = wv >> 1;

  auto stageA = [&](int ks, int buf) {
    const unsigned short* Ab = (ks < 4) ? mrm : xin;
    int kc = (ks & 3) * 32;
    #pragma unroll
    for (int i = 0; i < 2; i++) {
      int g16 = wv * 2 + i;
      const unsigned short* g =
          Ab + (size_t)(row0 + g16 * 16 + (l & 15)) * FD + kc + (l >> 4) * 8;
      __builtin_amdgcn_global_load_lds(
          (const __attribute__((address_space(1))) void*)g,
          (__attribute__((address_space(3))) void*)(AsL + buf * 4096 + g16 * 512),
          16, 0, 0);
    }
  };

  auto stageW = [&](int ks, int buf) {
    const short* src = Wc + ks * 8192 + wv * 2048;
    short* dst = WfL + buf * 8192 + wv * 2048;
    #pragma unroll
    for (int i = 0; i < 4; i++) {
      __builtin_amdgcn_global_load_lds(
          (const __attribute__((address_space(1))) void*)(src + i * 512 + l * 8),
          (__attribute__((address_space(3))) void*)(dst + i * 512),
          16, 0, 0);
    }
  };

  floatx4 acc[4][4];
  #pragma unroll
  for (int i = 0; i < 4; i++)
    #pragma unroll
    for (int q = 0; q < 4; q++) acc[i][q] = (floatx4)0.f;

  stageA(0, 0);
  stageW(0, 0);
  for (int ks = 0; ks < 8; ks++) {
    int buf = ks & 1;
    __syncthreads();                 // stage(ks) drained; buf^1 readers done
    if (ks < 7) { stageA(ks + 1, buf ^ 1); stageW(ks + 1, buf ^ 1); }
    short8 Areg[4];
    #pragma unroll
    for (int i = 0; i < 4; i++)
      Areg[i] = *(const short8*)(AsL + buf * 4096 + (rhalf * 4 + i) * 512 + l * 8);
    const short* WB = WfL + buf * 8192;
    #pragma unroll
    for (int q = 0; q < 4; q++) {
      int nt = chalf * 4 + q;
      short8 whi = *(const short8*)(WB + nt * 512 + l * 8);
      short8 wlo = *(const short8*)(WB + 4096 + nt * 512 + l * 8);
      #pragma unroll
      for (int i = 0; i < 4; i++) {
        acc[i][q] = __builtin_amdgcn_mfma_f32_16x16x32_bf16(Areg[i], whi, acc[i][q], 0, 0, 0);
        acc[i][q] = __builtin_amdgcn_mfma_f32_16x16x32_bf16(Areg[i], wlo, acc[i][q], 0, 0, 0);
      }
    }
  }

  // bias + relu in-register
  #pragma unroll
  for (int q = 0; q < 4; q++) {
    int col = chalf * 64 + q * 16 + (l & 15);
    float b = bias[col];
    #pragma unroll
    for (int i = 0; i < 4; i++)
      #pragma unroll
      for (int r = 0; r < 4; r++)
        acc[i][q][r] = fmaxf(acc[i][q][r] + b, 0.f);
  }

  // emit bf16 (+ optional fp8) via LDS transpose, one 64-col half at a time
  #pragma unroll
  for (int ph = 0; ph < 2; ph++) {
    __syncthreads();
    if (chalf == ph) {
      #pragma unroll
      for (int i = 0; i < 4; i++)
        #pragma unroll
        for (int q = 0; q < 4; q++)
          #pragma unroll
          for (int r = 0; r < 4; r++)
            S[(rhalf * 64 + i * 16 + (l >> 4) * 4 + r) * 64 + q * 16 + (l & 15)] = acc[i][q][r];
    }
    __syncthreads();
    #pragma unroll
    for (int it = 0; it < 4; it++) {
      int u = it * 256 + tid;
      int m = u & 15;
      int kb = (u >> 4) & 7;
      int grp = u >> 7;                    // 0..7
      int rl = grp * 16 + m;
      if (row0 + rl < n) {
        short8 s;
        union { unsigned char c[8]; uint2 uu; } e8;
        #pragma unroll
        for (int j = 0; j < 8; j++) {
          float v = S[rl * 64 + kb * 8 + j];
          s[j] = f2bf(v);
          e8.c[j] = ftof8(v);
        }
        *(short8*)(obf + (size_t)(row0 + rl) * FD + ph * 64 + kb * 8) = s;
        if (oq)
          *(uint2*)(oq + (size_t)(row0 + rl) * FD + ph * 64 + kb * 8) = e8.uu;
      }
    }
  }
}

// ---------------- pool stage 1: dense per-chunk partials, no atomics ----------------
__global__ __launch_bounds__(256) void k_pool1(
    const unsigned short* __restrict__ x0, const unsigned short* __restrict__ x1,
    const int* __restrict__ b0, const int* __restrict__ b1,
    float* __restrict__ part, int n, int NCH) {
  __shared__ float R[8][128];
  __shared__ int sb;
  int bx = (int)blockIdx.x;
  int t = bx & 1;
  int ch = bx >> 1;
  const unsigned short* x = t ? x1 : x0;
  const int* batch = t ? b1 : b0;
  float* P = part + ((size_t)t * NCH + ch) * 272;
  int tid = (int)threadIdx.x;
  int tx = tid & 31, rs = tid >> 5;
  int c4 = tx * 4;
  int start = ch * 128;
  int end = min(start + 128, n);

  int g0 = batch[start];
  int g1 = batch[end - 1];
  int lo[2], hi[2];
  int nruns;
  if (g0 == g1) {
    lo[0] = start; hi[0] = end; nruns = 1;
  } else {
    if (tid == 0) sb = end;
    __syncthreads();
    for (int i = start + tid + 1; i < end; i += 256)
      if (batch[i] != batch[i - 1]) atomicMin(&sb, i);
    __syncthreads();
    int b = sb;
    lo[0] = start; hi[0] = b; lo[1] = b; hi[1] = end; nruns = 2;
  }

  for (int run = 0; run < nruns; run++) {
    float4 a = make_float4(0.f, 0.f, 0.f, 0.f);
    for (int i = lo[run] + rs; i < hi[run]; i += 8) {
      ushort4 u = *(const ushort4*)&x[(size_t)i * FD + c4];
      a.x += bfu(u.x); a.y += bfu(u.y); a.z += bfu(u.z); a.w += bfu(u.w);
    }
    *(float4*)&R[rs][c4] = a;
    __syncthreads();
    if (tid < 128) {
      float s = 0.f;
      #pragma unroll
      for (int r = 0; r < 8; r++) s += R[r][tid];
      P[run * 128 + tid] = s;
    }
    __syncthreads();
  }
  if (tid == 0) {
    P[256] = (float)g0;
    P[257] = (float)(hi[0] - lo[0]);
    P[258] = (nruns == 2) ? (float)g1 : -1.f;
    P[259] = (nruns == 2) ? (float)(hi[1] - lo[1]) : 0.f;
  }
}

// ---------------- pool stage 2: reduce chunk partials (few atomics) ----------------
__global__ __launch_bounds__(128) void k_pool2(
    const float* __restrict__ part, float* __restrict__ pool,
    float* __restrict__ pcnt, int NCH, int CPS) {
  int bx = (int)blockIdx.x;
  int t = bx & 1;
  int seg = bx >> 1;
  int c0 = seg * CPS;
  int c1 = min(c0 + CPS, NCH);
  int tid = (int)threadIdx.x;
  float* pl = pool + t * NG * FD;
  float* pc = pcnt + t * NG;
  float acc = 0.f, ccnt = 0.f;
  int curg = -1;
  for (int ch = c0; ch < c1; ch++) {
    const float* P = part + ((size_t)t * NCH + ch) * 272;
    #pragma unroll
    for (int r = 0; r < 2; r++) {
      int g = (int)P[256 + r * 2];
      if (g < 0) continue;
      if (g != curg) {
        if (curg >= 0) {
          atomicAdd(&pl[curg * FD + tid], acc);
          if (tid == 0) atomicAdd(&pc[curg], ccnt);
        }
        curg = g; acc = 0.f; ccnt = 0.f;
      }
      acc += P[r * 128 + tid];
      if (tid == 0) ccnt += P[257 + r * 2];
    }
  }
  if (curg >= 0) {
    atomicAdd(&pl[curg * FD + tid], acc);
    if (tid == 0) atomicAdd(&pc[curg], ccnt);
  }
}

// ---------------- head ----------------
__global__ void k_final(const float* __restrict__ pool, const float* __restrict__ pcnt,
                        const float* __restrict__ linW, const float* __restrict__ linb,
                        float* __restrict__ out) {
  int tid = (int)threadIdx.x;
  if (tid < NG * 2) {
    int g = tid >> 1, o = tid & 1;
    float s = linb[o];
    for (int t = 0; t < 2; t++) {
      float inv = 1.f / fmaxf(pcnt[t * NG + g], 1.f);
      for (int d = 0; d < FD; d++) {
        float h = pool[(t * NG + g) * FD + d] * inv;
        s = fmaf(h, linW[(t * FD + d) * 2 + o], s);
      }
    }
    out[g * 2 + o] = s;
  }
}

extern "C" void kernel_launch(void* const* d_in, const int* in_sizes, int n_in,
                              void* d_out, int out_size, void* d_ws, size_t ws_size,
                              hipStream_t stream) {
  const float* x_in[2] = {(const float*)d_in[0], (const float*)d_in[1]};
  const float* Wl   = (const float*)d_in[2];
  const float* bl   = (const float*)d_in[3];
  const float* Wr   = (const float*)d_in[4];
  const float* linW = (const float*)d_in[5];
  const float* linb = (const float*)d_in[6];
  const int* edges[2] = {(const int*)d_in[7], (const int*)d_in[8]};
  const int* batch[2] = {(const int*)d_in[9], (const int*)d_in[10]};

  const int N = in_sizes[0] / FD;    // 50000
  const int E = in_sizes[7] / 2;     // 800000
  const int NGRP = (N + 15) / 16;    // 3125
  const int NTILE = (N + 127) / 128; // 391
  const int NCH = (N + 127) / 128;   // 391
  const int NBUCK = (N + 255) / 256; // 196
  const int CAP = 5120;              // per-bucket capacity (avg ~4096)
  const int NPAD = NTILE * 128;      // padded node count (A reads stay in-bounds)

  // ---- workspace layout (512B aligned) ----
  char* p = (char*)d_ws;
  auto alloc = [&](size_t bytes) -> char* {
    char* r = p; p += (bytes + 511) & ~(size_t)511; return r;
  };
  int* gcount  = (int*)alloc(2 * 256 * 4);
  float* pool  = (float*)alloc(2 * NG * FD * 4);
  float* pcnt  = (float*)alloc(2 * NG * 4);
  size_t zero_bytes = (size_t)(p - (char*)d_ws);       // gcount+pool+pcnt
  int* off[2];  off[0]  = (int*)alloc((size_t)N * 4); off[1]  = (int*)alloc((size_t)N * 4);
  int* deg[2];  deg[0]  = (int*)alloc((size_t)N * 4); deg[1]  = (int*)alloc((size_t)N * 4);
  int* buckets = (int*)alloc((size_t)2 * NBUCK * CAP * 4);
  unsigned short* csr[2];
  csr[0] = (unsigned short*)alloc((size_t)NBUCK * CAP * 2);
  csr[1] = (unsigned short*)alloc((size_t)NBUCK * CAP * 2);
  float* part  = (float*)alloc((size_t)2 * NCH * 272 * 4);
  short* Wf    = (short*)alloc((size_t)6 * 65536 * 2);
  short* meanb[2];
  meanb[0] = (short*)alloc((size_t)NPAD * FD * 2);
  meanb[1] = (short*)alloc((size_t)NPAD * FD * 2);
  short* xbf[2][2];
  unsigned char* xq[2][2];
  for (int t = 0; t < 2; t++)
    for (int b = 0; b < 2; b++) {
      xbf[t][b] = (short*)alloc((size_t)NPAD * FD * 2);
      xq[t][b]  = (unsigned char*)alloc((size_t)NPAD * FD);
    }
  if ((size_t)(p - (char*)d_ws) > ws_size) return;     // insufficient workspace

  hipMemsetAsync(d_ws, 0, zero_bytes, stream);

  // conversions (merged) + CSR build
  k_conv<<<192 + 2 * NGRP, 256, 0, stream>>>(Wl, Wr, Wf, x_in[0], x_in[1],
                                             xbf[0][0], xbf[1][0],
                                             xq[0][0], xq[1][0], N);
  int bblocks = 2 * ((E + 4095) / 4096);
  k_bucket<<<bblocks, 256, 0, stream>>>(edges[0], edges[1], gcount, buckets, E, NBUCK, CAP);
  k_csr<<<2 * NBUCK, 256, 0, stream>>>(gcount, buckets, csr[0], csr[1],
                                       off[0], off[1], deg[0], deg[1], NBUCK, CAP, N);

  int pp = 0;
  for (int l = 0; l < NL; l++) {
    int last = (l == NL - 1);
    k_agg<<<2 * NGRP, 512, 0, stream>>>(
        xq[0][pp], xq[1][pp],
        csr[0], csr[1], off[0], off[1], deg[0], deg[1], meanb[0], meanb[1], N);
    k_gemm<<<2 * NTILE, 256, 0, stream>>>(
        (const unsigned short*)meanb[0], (const unsigned short*)meanb[1],
        (const unsigned short*)xbf[0][pp], (const unsigned short*)xbf[1][pp],
        Wf + (size_t)l * 2 * 65536, bl + (size_t)l * 2 * FD,
        xbf[0][pp ^ 1], xbf[1][pp ^ 1],
        last ? nullptr : xq[0][pp ^ 1], last ? nullptr : xq[1][pp ^ 1], N);
    pp ^= 1;
  }

  k_pool1<<<2 * NCH, 256, 0, stream>>>(
      (const unsigned short*)xbf[0][pp], (const unsigned short*)xbf[1][pp],
      batch[0], batch[1], part, N, NCH);
  int CPS = (NCH + 7) / 8;
  k_pool2<<<16, 128, 0, stream>>>(part, pool, pcnt, NCH, CPS);
  k_final<<<1, 64, 0, stream>>>(pool, pcnt, linW, linb, (float*)d_out);
}

// Round 16
// 416.044 us; speedup vs baseline: 1.2536x; 1.0008x over previous
//
#include <hip/hip_runtime.h>
#include <hip/hip_bf16.h>
#include <hip/hip_fp8.h>
#include <cstdint>
#include <cstddef>

static constexpr int FD = 128;   // feature dim
static constexpr int NG = 16;    // graphs per batch
static constexpr int NL = 3;     // layers

typedef __attribute__((ext_vector_type(8))) short short8;
typedef __attribute__((ext_vector_type(4))) float floatx4;

__device__ __forceinline__ short f2bf(float v) {
  union { __hip_bfloat16 b; short s; } u;
  u.b = __float2bfloat16(v);
  return u.s;
}
__device__ __forceinline__ float bfu(unsigned short u) {
  return __uint_as_float((unsigned int)u << 16);
}
__device__ __forceinline__ unsigned char ftof8(float v) {
  __hip_fp8_e4m3 f(v);
  return f.__x;
}
__device__ __forceinline__ float f8tof(unsigned char v) {
  __hip_fp8_e4m3 f;
  f.__x = v;
  return (float)f;
}

// packed fp8 <-> f32 via HW cvt (falls back to class path if builtin absent)
__device__ __forceinline__ float4 f8x4(unsigned int w) {
#if __has_builtin(__builtin_amdgcn_cvt_pk_f32_fp8)
  typedef __attribute__((ext_vector_type(2))) float floatx2;
  floatx2 lo = __builtin_amdgcn_cvt_pk_f32_fp8((int)w, false);
  floatx2 hi = __builtin_amdgcn_cvt_pk_f32_fp8((int)w, true);
  return make_float4(lo[0], lo[1], hi[0], hi[1]);
#else
  return make_float4(f8tof(w & 0xff), f8tof((w >> 8) & 0xff),
                     f8tof((w >> 16) & 0xff), f8tof((w >> 24) & 0xff));
#endif
}
__device__ __forceinline__ unsigned int f32x4tof8(float a, float b, float c, float d) {
#if __has_builtin(__builtin_amdgcn_cvt_pk_fp8_f32)
  int v = __builtin_amdgcn_cvt_pk_fp8_f32(a, b, 0, false);
  v = __builtin_amdgcn_cvt_pk_fp8_f32(c, d, v, true);
  return (unsigned int)v;
#else
  return (unsigned int)ftof8(a) | ((unsigned int)ftof8(b) << 8) |
         ((unsigned int)ftof8(c) << 16) | ((unsigned int)ftof8(d) << 24);
#endif
}

// ---------------- pass A: bucket edges by dst>>8, LDS-sorted staging ----------------
// entry = src | (dst<<16)  (requires N <= 65536)
__global__ __launch_bounds__(256) void k_bucket(
    const int* __restrict__ e0, const int* __restrict__ e1,
    int* __restrict__ gcount, int* __restrict__ buckets,
    int E, int NBUCK, int CAP)
{
  __shared__ int hist[256], lexcl[256], gbase[256], wcur[256];
  __shared__ int staged[4096];
  __shared__ int wsum[4];
  __shared__ int totalS;
  int tid = (int)threadIdx.x;
  int bx = (int)blockIdx.x;
  int t = bx & 1;
  int chunk = (bx >> 1) * 4096;
  const int* eg = t ? e1 : e0;
  hist[tid] = 0;
  __syncthreads();
  unsigned int ent[16];
  #pragma unroll
  for (int k = 0; k < 16; k++) {
    int i = chunk + k * 256 + tid;
    if (i < E) {
      unsigned int src = (unsigned int)eg[i];
      unsigned int dst = (unsigned int)eg[E + i];
      ent[k] = src | (dst << 16);
      atomicAdd(&hist[dst >> 8], 1);
    } else ent[k] = 0xFFFFFFFFu;
  }
  __syncthreads();
  // block scan of hist[256]
  int lane = tid & 63, wv = tid >> 6;
  int v = hist[tid];
  int sc = v;
  #pragma unroll
  for (int d = 1; d < 64; d <<= 1) {
    int tt = __shfl_up(sc, d, 64);
    if (lane >= d) sc += tt;
  }
  if (lane == 63) wsum[wv] = sc;
  __syncthreads();
  int wpre = 0;
  for (int w = 0; w < wv; w++) wpre += wsum[w];
  int excl = wpre + sc - v;
  lexcl[tid] = excl;
  wcur[tid] = excl;
  gbase[tid] = v ? atomicAdd(&gcount[t * 256 + tid], v) : 0;
  if (tid == 255) totalS = excl + v;
  __syncthreads();
  #pragma unroll
  for (int k = 0; k < 16; k++) {
    if (ent[k] != 0xFFFFFFFFu) {
      int b = ent[k] >> 24;
      int pos = atomicAdd(&wcur[b], 1);
      staged[pos] = (int)ent[k];
    }
  }
  __syncthreads();
  int total = totalS;
  for (int j = tid; j < total; j += 256) {
    unsigned int e = (unsigned int)staged[j];
    int b = e >> 24;
    int gp = gbase[b] + (j - lexcl[b]);
    if (gp < CAP) buckets[((size_t)t * NBUCK + b) * CAP + gp] = (int)e;
  }
}

// ---------------- pass B: per-bucket deg/off/csr with LDS atomics only ----------------
__global__ __launch_bounds__(256) void k_csr(
    const int* __restrict__ gcount, const int* __restrict__ buckets,
    unsigned short* __restrict__ csr0, unsigned short* __restrict__ csr1,
    int* __restrict__ off0, int* __restrict__ off1,
    int* __restrict__ deg0, int* __restrict__ deg1,
    int NBUCK, int CAP, int n)
{
  __shared__ int hist[256], wcur[256], wsum[4];
  int tid = (int)threadIdx.x;
  int bx = (int)blockIdx.x;
  int t = bx & 1;
  int b = bx >> 1;
  int cnt = gcount[t * 256 + b];
  if (cnt > CAP) cnt = CAP;
  const int* base = buckets + ((size_t)t * NBUCK + b) * CAP;
  unsigned short* csr = t ? csr1 : csr0;
  int* off = t ? off1 : off0;
  int* deg = t ? deg1 : deg0;
  hist[tid] = 0;
  __syncthreads();
  for (int j = tid; j < cnt; j += 256)
    atomicAdd(&hist[((unsigned int)base[j] >> 16) & 255], 1);
  __syncthreads();
  int lane = tid & 63, wv = tid >> 6;
  int v = hist[tid];
  int sc = v;
  #pragma unroll
  for (int d = 1; d < 64; d <<= 1) {
    int tt = __shfl_up(sc, d, 64);
    if (lane >= d) sc += tt;
  }
  if (lane == 63) wsum[wv] = sc;
  __syncthreads();
  int wpre = 0;
  for (int w = 0; w < wv; w++) wpre += wsum[w];
  int excl = wpre + sc - v;
  wcur[tid] = excl;
  int node = b * 256 + tid;
  if (node < n) { deg[node] = v; off[node] = b * CAP + excl; }
  __syncthreads();
  for (int j = tid; j < cnt; j += 256) {
    unsigned int e = (unsigned int)base[j];
    int ld = (e >> 16) & 255;
    int pos = atomicAdd(&wcur[ld], 1);
    csr[b * CAP + pos] = (unsigned short)(e & 0xFFFFu);
  }
}

// ---------------- merged conversion: W -> frag hi/lo, x -> bf16 + fp8 ----------------
// blocks [0,192): wconv; blocks [192, 192+2*NGRP): xconv
__global__ __launch_bounds__(256) void k_conv(
    const float* __restrict__ Wl, const float* __restrict__ Wr,
    short* __restrict__ Wf,
    const float* __restrict__ x0, const float* __restrict__ x1,
    short* __restrict__ r0, short* __restrict__ r1,
    unsigned char* __restrict__ q0, unsigned char* __restrict__ q1, int n) {
  int bx = (int)blockIdx.x;
  int tid = (int)threadIdx.x;
  if (bx < 192) {
    int u = bx * 256 + tid;
    int combo = u >> 13;
    int r = u & 8191;
    int l  = r & 63;
    int nt = (r >> 6) & 7;
    int h  = (r >> 9) & 1;
    int ks = r >> 10;
    short8 s;
    #pragma unroll
    for (int j = 0; j < 8; j++) {
      int k = ks * 32 + (l >> 4) * 8 + j;
      int nn = nt * 16 + (l & 15);
      float w = (k < FD) ? Wl[((size_t)combo * FD + k) * FD + nn]
                         : Wr[((size_t)combo * FD + (k - FD)) * FD + nn];
      __hip_bfloat16 hb = __float2bfloat16(w);
      if (h == 0) {
        union { __hip_bfloat16 b; short t; } uu; uu.b = hb; s[j] = uu.t;
      } else {
        float hf = __bfloat162float(hb);
        s[j] = f2bf(w - hf);
      }
    }
    *(short8*)(Wf + (size_t)combo * 65536 + (size_t)r * 8) = s;
  } else {
    int b2 = bx - 192;
    int t = b2 & 1;
    int g = b2 >> 1;
    const float* x = t ? x1 : x0;
    short* rm = t ? r1 : r0;
    unsigned char* qm = t ? q1 : q0;
    int m = tid & 15;
    int kb = tid >> 4;          // 0..15
    int node = g * 16 + m;
    if (node >= n) return;
    const float* src = x + (size_t)node * FD + kb * 8;
    short8 s;
    float v[8];
    #pragma unroll
    for (int j = 0; j < 8; j++) {
      v[j] = src[j];
      s[j] = f2bf(v[j]);
    }
    uint2 e8;
    e8.x = f32x4tof8(v[0], v[1], v[2], v[3]);
    e8.y = f32x4tof8(v[4], v[5], v[6], v[7]);
    *(short8*)(rm + (size_t)node * FD + kb * 8) = s;
    *(uint2*)(qm + (size_t)node * FD + kb * 8) = e8;
  }
}

// ---------------- neighbor mean from fp8 rows -> row-major bf16 mean ----------------
// 16 nodes/block, 512 threads, 32 lanes/node, 8-deep gather pipeline
// (R14-proven structure; decode via packed HW cvt).
__global__ __launch_bounds__(512) void k_agg(
    const unsigned char* __restrict__ x0, const unsigned char* __restrict__ x1,
    const unsigned short* __restrict__ csr0, const unsigned short* __restrict__ csr1,
    const int* __restrict__ off0, const int* __restrict__ off1,
    const int* __restrict__ deg0, const int* __restrict__ deg1,
    short* __restrict__ m0, short* __restrict__ m1, int n)
{
  __shared__ float M[16][132];
  int bx = blockIdx.x;
  int t = bx & 1;
  int g = bx >> 1;
  const unsigned char* x = t ? x1 : x0;
  const unsigned short* csr = t ? csr1 : csr0;
  const int* off  = t ? off1 : off0;
  const int* deg  = t ? deg1 : deg0;
  short* mrm      = t ? m1 : m0;
  int tid = (int)threadIdx.x;
  int s = tid >> 5;             // node slot 0..15
  int tx = tid & 31;
  int c4 = tx * 4;
  int node = g * 16 + s;
  if (node < n) {
    int o = off[node], d = deg[node];
    float a0 = 0.f, a1 = 0.f, a2 = 0.f, a3 = 0.f;
    for (int k0 = 0; k0 < d; k0 += 32) {
      int idx = (k0 + tx < d) ? (int)csr[o + k0 + tx] : 0;
      int mm = min(32, d - k0);
      int j = 0;
      for (; j + 8 <= mm; j += 8) {
        int s0 = __shfl(idx, j + 0, 32);
        int s1 = __shfl(idx, j + 1, 32);
        int s2 = __shfl(idx, j + 2, 32);
        int s3 = __shfl(idx, j + 3, 32);
        int s4 = __shfl(idx, j + 4, 32);
        int s5 = __shfl(idx, j + 5, 32);
        int s6 = __shfl(idx, j + 6, 32);
        int s7 = __shfl(idx, j + 7, 32);
        unsigned int w0 = *(const unsigned int*)&x[(size_t)s0 * FD + c4];
        unsigned int w1 = *(const unsigned int*)&x[(size_t)s1 * FD + c4];
        unsigned int w2 = *(const unsigned int*)&x[(size_t)s2 * FD + c4];
        unsigned int w3 = *(const unsigned int*)&x[(size_t)s3 * FD + c4];
        unsigned int w4 = *(const unsigned int*)&x[(size_t)s4 * FD + c4];
        unsigned int w5 = *(const unsigned int*)&x[(size_t)s5 * FD + c4];
        unsigned int w6 = *(const unsigned int*)&x[(size_t)s6 * FD + c4];
        unsigned int w7 = *(const unsigned int*)&x[(size_t)s7 * FD + c4];
        float4 v0 = f8x4(w0);
        float4 v1 = f8x4(w1);
        float4 v2 = f8x4(w2);
        float4 v3 = f8x4(w3);
        float4 v4 = f8x4(w4);
        float4 v5 = f8x4(w5);
        float4 v6 = f8x4(w6);
        float4 v7 = f8x4(w7);
        a0 += ((v0.x + v1.x) + (v2.x + v3.x)) + ((v4.x + v5.x) + (v6.x + v7.x));
        a1 += ((v0.y + v1.y) + (v2.y + v3.y)) + ((v4.y + v5.y) + (v6.y + v7.y));
        a2 += ((v0.z + v1.z) + (v2.z + v3.z)) + ((v4.z + v5.z) + (v6.z + v7.z));
        a3 += ((v0.w + v1.w) + (v2.w + v3.w)) + ((v4.w + v5.w) + (v6.w + v7.w));
      }
      for (; j < mm; j++) {
        int si = __shfl(idx, j, 32);
        float4 v = f8x4(*(const unsigned int*)&x[(size_t)si * FD + c4]);
        a0 += v.x; a1 += v.y; a2 += v.z; a3 += v.w;
      }
    }
    float inv = 1.f / fmaxf((float)d, 1.f);
    M[s][c4 + 0] = a0 * inv;
    M[s][c4 + 1] = a1 * inv;
    M[s][c4 + 2] = a2 * inv;
    M[s][c4 + 3] = a3 * inv;
  }
  __syncthreads();
  if (tid < 256) {
    int m = tid & 15;
    int kb = tid >> 4;          // 0..15
    int nd = g * 16 + m;
    if (nd < n) {
      short8 v;
      #pragma unroll
      for (int j = 0; j < 8; j++) v[j] = f2bf(M[m][kb * 8 + j]);
      *(short8*)(mrm + (size_t)nd * FD + kb * 8) = v;
    }
  }
}

// ---------------- MFMA GEMM: y = relu([mean|x] @ [Wl;Wr] + b) -> bf16 + fp8 ----------------
__global__ __launch_bounds__(256) void k_gemm(
    const unsigned short* __restrict__ mrm0, const unsigned short* __restrict__ mrm1,
    const unsigned short* __restrict__ xin0, const unsigned short* __restrict__ xin1,
    const short* __restrict__ Wf,       // layer base: [2 types][65536]
    const float* __restrict__ bl,       // layer base: [2 types][128]
    short* __restrict__ obf0, short* __restrict__ obf1,
    unsigned char* __restrict__ oq0, unsigned char* __restrict__ oq1, int n)
{
  __shared__ __align__(16) char smem[49152];
  short* AsL = (short*)smem;            // [2][4096] A dbuf (16 KB)
  short* WfL = (short*)(smem + 16384);  // [2][8192] W dbuf (32 KB)
  float* S   = (float*)smem;            // [128][64] epilogue scratch (after loop)

  int tid = (int)threadIdx.x;
  int l = tid & 63;
  int wv = tid >> 6;
  int bx = (int)blockIdx.x;
  int t = bx & 1;
  int tile = bx >> 1;
  int row0 = tile * 128;

  const unsigned short* mrm = t ? mrm1 : mrm0;
  const unsigned short* xin = t ? xin1 : xin0;
  const short* Wc  = Wf + (size_t)t * 65536;
  const float* bias = bl + t * FD;
  short* obf = t ? obf1 : obf0;
  unsigned char* oq = t ? oq1 : oq0;

  int rhalf = wv & 1;
  int chalf = wv >> 1;

  auto stageA = [&](int ks, int buf) {
    const unsigned short* Ab = (ks < 4) ? mrm : xin;
    int kc = (ks & 3) * 32;
    #pragma unroll
    for (int i = 0; i < 2; i++) {
      int g16 = wv * 2 + i;
      const unsigned short* g =
          Ab + (size_t)(row0 + g16 * 16 + (l & 15)) * FD + kc + (l >> 4) * 8;
      __builtin_amdgcn_global_load_lds(
          (const __attribute__((address_space(1))) void*)g,
          (__attribute__((address_space(3))) void*)(AsL + buf * 4096 + g16 * 512),
          16, 0, 0);
    }
  };

  auto stageW = [&](int ks, int buf) {
    const short* src = Wc + ks * 8192 + wv * 2048;
    short* dst = WfL + buf * 8192 + wv * 2048;
    #pragma unroll
    for (int i = 0; i < 4; i++) {
      __builtin_amdgcn_global_load_lds(
          (const __attribute__((address_space(1))) void*)(src + i * 512 + l * 8),
          (__attribute__((address_space(3))) void*)(dst + i * 512),
          16, 0, 0);
    }
  };

  floatx4 acc[4][4];
  #pragma unroll
  for (int i = 0; i < 4; i++)
    #pragma unroll
    for (int q = 0; q < 4; q++) acc[i][q] = (floatx4)0.f;

  stageA(0, 0);
  stageW(0, 0);
  for (int ks = 0; ks < 8; ks++) {
    int buf = ks & 1;
    __syncthreads();                 // stage(ks) drained; buf^1 readers done
    if (ks < 7) { stageA(ks + 1, buf ^ 1); stageW(ks + 1, buf ^ 1); }
    short8 Areg[4];
    #pragma unroll
    for (int i = 0; i < 4; i++)
      Areg[i] = *(const short8*)(AsL + buf * 4096 + (rhalf * 4 + i) * 512 + l * 8);
    const short* WB = WfL + buf * 8192;
    #pragma unroll
    for (int q = 0; q < 4; q++) {
      int nt = chalf * 4 + q;
      short8 whi = *(const short8*)(WB + nt * 512 + l * 8);
      short8 wlo = *(const short8*)(WB + 4096 + nt * 512 + l * 8);
      #pragma unroll
      for (int i = 0; i < 4; i++) {
        acc[i][q] = __builtin_amdgcn_mfma_f32_16x16x32_bf16(Areg[i], whi, acc[i][q], 0, 0, 0);
        acc[i][q] = __builtin_amdgcn_mfma_f32_16x16x32_bf16(Areg[i], wlo, acc[i][q], 0, 0, 0);
      }
    }
  }

  // bias + relu in-register
  #pragma unroll
  for (int q = 0; q < 4; q++) {
    int col = chalf * 64 + q * 16 + (l & 15);
    float b = bias[col];
    #pragma unroll
    for (int i = 0; i < 4; i++)
      #pragma unroll
      for (int r = 0; r < 4; r++)
        acc[i][q][r] = fmaxf(acc[i][q][r] + b, 0.f);
  }

  // emit bf16 (+ optional fp8) via LDS transpose, one 64-col half at a time
  #pragma unroll
  for (int ph = 0; ph < 2; ph++) {
    __syncthreads();
    if (chalf == ph) {
      #pragma unroll
      for (int i = 0; i < 4; i++)
        #pragma unroll
        for (int q = 0; q < 4; q++)
          #pragma unroll
          for (int r = 0; r < 4; r++)
            S[(rhalf * 64 + i * 16 + (l >> 4) * 4 + r) * 64 + q * 16 + (l & 15)] = acc[i][q][r];
    }
    __syncthreads();
    #pragma unroll
    for (int it = 0; it < 4; it++) {
      int u = it * 256 + tid;
      int m = u & 15;
      int kb = (u >> 4) & 7;
      int grp = u >> 7;                    // 0..7
      int rl = grp * 16 + m;
      if (row0 + rl < n) {
        short8 s;
        float v[8];
        #pragma unroll
        for (int j = 0; j < 8; j++) {
          v[j] = S[rl * 64 + kb * 8 + j];
          s[j] = f2bf(v[j]);
        }
        *(short8*)(obf + (size_t)(row0 + rl) * FD + ph * 64 + kb * 8) = s;
        if (oq) {
          uint2 e8;
          e8.x = f32x4tof8(v[0], v[1], v[2], v[3]);
          e8.y = f32x4tof8(v[4], v[5], v[6], v[7]);
          *(uint2*)(oq + (size_t)(row0 + rl) * FD + ph * 64 + kb * 8) = e8;
        }
      }
    }
  }
}

// ---------------- pool stage 1: dense per-chunk partials, no atomics ----------------
__global__ __launch_bounds__(256) void k_pool1(
    const unsigned short* __restrict__ x0, const unsigned short* __restrict__ x1,
    const int* __restrict__ b0, const int* __restrict__ b1,
    float* __restrict__ part, int n, int NCH) {
  __shared__ float R[8][128];
  __shared__ int sb;
  int bx = (int)blockIdx.x;
  int t = bx & 1;
  int ch = bx >> 1;
  const unsigned short* x = t ? x1 : x0;
  const int* batch = t ? b1 : b0;
  float* P = part + ((size_t)t * NCH + ch) * 272;
  int tid = (int)threadIdx.x;
  int tx = tid & 31, rs = tid >> 5;
  int c4 = tx * 4;
  int start = ch * 128;
  int end = min(start + 128, n);

  int g0 = batch[start];
  int g1 = batch[end - 1];
  int lo[2], hi[2];
  int nruns;
  if (g0 == g1) {
    lo[0] = start; hi[0] = end; nruns = 1;
  } else {
    if (tid == 0) sb = end;
    __syncthreads();
    for (int i = start + tid + 1; i < end; i += 256)
      if (batch[i] != batch[i - 1]) atomicMin(&sb, i);
    __syncthreads();
    int b = sb;
    lo[0] = start; hi[0] = b; lo[1] = b; hi[1] = end; nruns = 2;
  }

  for (int run = 0; run < nruns; run++) {
    float4 a = make_float4(0.f, 0.f, 0.f, 0.f);
    for (int i = lo[run] + rs; i < hi[run]; i += 8) {
      ushort4 u = *(const ushort4*)&x[(size_t)i * FD + c4];
      a.x += bfu(u.x); a.y += bfu(u.y); a.z += bfu(u.z); a.w += bfu(u.w);
    }
    *(float4*)&R[rs][c4] = a;
    __syncthreads();
    if (tid < 128) {
      float s = 0.f;
      #pragma unroll
      for (int r = 0; r < 8; r++) s += R[r][tid];
      P[run * 128 + tid] = s;
    }
    __syncthreads();
  }
  if (tid == 0) {
    P[256] = (float)g0;
    P[257] = (float)(hi[0] - lo[0]);
    P[258] = (nruns == 2) ? (float)g1 : -1.f;
    P[259] = (nruns == 2) ? (float)(hi[1] - lo[1]) : 0.f;
  }
}

// ---------------- pool stage 2: reduce chunk partials (few atomics) ----------------
__global__ __launch_bounds__(128) void k_pool2(
    const float* __restrict__ part, float* __restrict__ pool,
    float* __restrict__ pcnt, int NCH, int CPS) {
  int bx = (int)blockIdx.x;
  int t = bx & 1;
  int seg = bx >> 1;
  int c0 = seg * CPS;
  int c1 = min(c0 + CPS, NCH);
  int tid = (int)threadIdx.x;
  float* pl = pool + t * NG * FD;
  float* pc = pcnt + t * NG;
  float acc = 0.f, ccnt = 0.f;
  int curg = -1;
  for (int ch = c0; ch < c1; ch++) {
    const float* P = part + ((size_t)t * NCH + ch) * 272;
    #pragma unroll
    for (int r = 0; r < 2; r++) {
      int g = (int)P[256 + r * 2];
      if (g < 0) continue;
      if (g != curg) {
        if (curg >= 0) {
          atomicAdd(&pl[curg * FD + tid], acc);
          if (tid == 0) atomicAdd(&pc[curg], ccnt);
        }
        curg = g; acc = 0.f; ccnt = 0.f;
      }
      acc += P[r * 128 + tid];
      if (tid == 0) ccnt += P[257 + r * 2];
    }
  }
  if (curg >= 0) {
    atomicAdd(&pl[curg * FD + tid], acc);
    if (tid == 0) atomicAdd(&pc[curg], ccnt);
  }
}

// ---------------- head ----------------
__global__ void k_final(const float* __restrict__ pool, const float* __restrict__ pcnt,
                        const float* __restrict__ linW, const float* __restrict__ linb,
                        float* __restrict__ out) {
  int tid = (int)threadIdx.x;
  if (tid < NG * 2) {
    int g = tid >> 1, o = tid & 1;
    float s = linb[o];
    for (int t = 0; t < 2; t++) {
      float inv = 1.f / fmaxf(pcnt[t * NG + g], 1.f);
      for (int d = 0; d < FD; d++) {
        float h = pool[(t * NG + g) * FD + d] * inv;
        s = fmaf(h, linW[(t * FD + d) * 2 + o], s);
      }
    }
    out[g * 2 + o] = s;
  }
}

extern "C" void kernel_launch(void* const* d_in, const int* in_sizes, int n_in,
                              void* d_out, int out_size, void* d_ws, size_t ws_size,
                              hipStream_t stream) {
  const float* x_in[2] = {(const float*)d_in[0], (const float*)d_in[1]};
  const float* Wl   = (const float*)d_in[2];
  const float* bl   = (const float*)d_in[3];
  const float* Wr   = (const float*)d_in[4];
  const float* linW = (const float*)d_in[5];
  const float* linb = (const float*)d_in[6];
  const int* edges[2] = {(const int*)d_in[7], (const int*)d_in[8]};
  const int* batch[2] = {(const int*)d_in[9], (const int*)d_in[10]};

  const int N = in_sizes[0] / FD;    // 50000
  const int E = in_sizes[7] / 2;     // 800000
  const int NGRP = (N + 15) / 16;    // 3125
  const int NTILE = (N + 127) / 128; // 391
  const int NCH = (N + 127) / 128;   // 391
  const int NBUCK = (N + 255) / 256; // 196
  const int CAP = 5120;              // per-bucket capacity (avg ~4096)
  const int NPAD = NTILE * 128;      // padded node count (A reads stay in-bounds)

  // ---- workspace layout (512B aligned) ----
  char* p = (char*)d_ws;
  auto alloc = [&](size_t bytes) -> char* {
    char* r = p; p += (bytes + 511) & ~(size_t)511; return r;
  };
  int* gcount  = (int*)alloc(2 * 256 * 4);
  float* pool  = (float*)alloc(2 * NG * FD * 4);
  float* pcnt  = (float*)alloc(2 * NG * 4);
  size_t zero_bytes = (size_t)(p - (char*)d_ws);       // gcount+pool+pcnt
  int* off[2];  off[0]  = (int*)alloc((size_t)N * 4); off[1]  = (int*)alloc((size_t)N * 4);
  int* deg[2];  deg[0]  = (int*)alloc((size_t)N * 4); deg[1]  = (int*)alloc((size_t)N * 4);
  int* buckets = (int*)alloc((size_t)2 * NBUCK * CAP * 4);
  unsigned short* csr[2];
  csr[0] = (unsigned short*)alloc((size_t)NBUCK * CAP * 2);
  csr[1] = (unsigned short*)alloc((size_t)NBUCK * CAP * 2);
  float* part  = (float*)alloc((size_t)2 * NCH * 272 * 4);
  short* Wf    = (short*)alloc((size_t)6 * 65536 * 2);
  short* meanb[2];
  meanb[0] = (short*)alloc((size_t)NPAD * FD * 2);
  meanb[1] = (short*)alloc((size_t)NPAD * FD * 2);
  short* xbf[2][2];
  unsigned char* xq[2][2];
  for (int t = 0; t < 2; t++)
    for (int b = 0; b < 2; b++) {
      xbf[t][b] = (short*)alloc((size_t)NPAD * FD * 2);
      xq[t][b]  = (unsigned char*)alloc((size_t)NPAD * FD);
    }
  if ((size_t)(p - (char*)d_ws) > ws_size) return;     // insufficient workspace

  hipMemsetAsync(d_ws, 0, zero_bytes, stream);

  // conversions (merged) + CSR build
  k_conv<<<192 + 2 * NGRP, 256, 0, stream>>>(Wl, Wr, Wf, x_in[0], x_in[1],
                                             xbf[0][0], xbf[1][0],
                                             xq[0][0], xq[1][0], N);
  int bblocks = 2 * ((E + 4095) / 4096);
  k_bucket<<<bblocks, 256, 0, stream>>>(edges[0], edges[1], gcount, buckets, E, NBUCK, CAP);
  k_csr<<<2 * NBUCK, 256, 0, stream>>>(gcount, buckets, csr[0], csr[1],
                                       off[0], off[1], deg[0], deg[1], NBUCK, CAP, N);

  int pp = 0;
  for (int l = 0; l < NL; l++) {
    int last = (l == NL - 1);
    k_agg<<<2 * NGRP, 512, 0, stream>>>(
        xq[0][pp], xq[1][pp],
        csr[0], csr[1], off[0], off[1], deg[0], deg[1], meanb[0], meanb[1], N);
    k_gemm<<<2 * NTILE, 256, 0, stream>>>(
        (const unsigned short*)meanb[0], (const unsigned short*)meanb[1],
        (const unsigned short*)xbf[0][pp], (const unsigned short*)xbf[1][pp],
        Wf + (size_t)l * 2 * 65536, bl + (size_t)l * 2 * FD,
        xbf[0][pp ^ 1], xbf[1][pp ^ 1],
        last ? nullptr : xq[0][pp ^ 1], last ? nullptr : xq[1][pp ^ 1], N);
    pp ^= 1;
  }

  k_pool1<<<2 * NCH, 256, 0, stream>>>(
      (const unsigned short*)xbf[0][pp], (const unsigned short*)xbf[1][pp],
      batch[0], batch[1], part, N, NCH);
  int CPS = (NCH + 7) / 8;
  k_pool2<<<16, 128, 0, stream>>>(part, pool, pcnt, NCH, CPS);
  k_final<<<1, 64, 0, stream>>>(pool, pcnt, linW, linb, (float*)d_out);
}